// Round 19
// baseline (46.412 us; speedup 1.0000x reference)
//
#include <hip/hip_runtime.h>
#include <math.h>

#define DD  256
#define LKK 512
#define LQQ 256
#define BB  4

constexpr float TWO_LOG2E = 2.8853900817779268f;  // 2*log2(e)
constexpr float LOG2E     = 1.4426950408889634f;

__device__ __forceinline__ float fast_rcp(float x)  { return __builtin_amdgcn_rcpf(x); }
__device__ __forceinline__ float fast_exp2(float x) { return __builtin_amdgcn_exp2f(x); }

// Force a (wave-uniform) pointer into SGPRs so uniform loads can go scalar.
__device__ __forceinline__ const float* uni(const float* p) {
  unsigned long long a = (unsigned long long)p;
  unsigned lo = __builtin_amdgcn_readfirstlane((unsigned)a);
  unsigned hi = __builtin_amdgcn_readfirstlane((unsigned)(a >> 32));
  return (const float*)(((unsigned long long)hi << 32) | lo);
}

#define COMP(v,u) ((u)==0?(v).x:(u)==1?(v).y:(u)==2?(v).z:(v).w)

// EaT[b][e][k] = exp(2 * key[b,k,:] . W1[e,:])  (fp32, d-major / transposed)
// Eb [b*LQ+q][e] = exp(2 * query[b,q,:] . W2[e,:])  (fp32, row-major)
// R14 config verbatim (measured best): BK=32, 32m x 64e tiles, (96,4) grid.
__global__ __launch_bounds__(256) void gemm_expk2(const float* __restrict__ key,
                                                  const float* __restrict__ query,
                                                  const float* __restrict__ W1,
                                                  const float* __restrict__ W2,
                                                  float* __restrict__ EaT,
                                                  float* __restrict__ Eb) {
  __shared__ float Xs[32][36];
  __shared__ float Ws[32][68];
  const int tid = threadIdx.x;
  const bool isK = blockIdx.x < (BB * LKK / 32);
  const float* __restrict__ X = isK ? key : query;
  const float* __restrict__ W = isK ? W1 : W2;
  const int m0 = (isK ? blockIdx.x : blockIdx.x - BB * LKK / 32) * 32;
  const int e0 = blockIdx.y * 64;

  const int r0 = (tid >> 4) << 1;   // 0..30
  const int c0 = (tid & 15) << 2;   // 0..60
  const int xr = tid >> 3, xc = (tid & 7) << 2;   // 32 rows x 32 k via float4
  const int wr = tid >> 2, wc = (tid & 3) << 3;   // 64 rows x 32 k via 2x float4

  float4 xv  = *(const float4*)&X[(m0 + xr) * DD + xc];
  float4 wv0 = *(const float4*)&W[(e0 + wr) * DD + wc];
  float4 wv1 = *(const float4*)&W[(e0 + wr) * DD + wc + 4];

  float acc[2][4] = {};
  for (int k0 = 0; k0 < DD; k0 += 32) {
    __syncthreads();
    Xs[xc + 0][xr] = xv.x; Xs[xc + 1][xr] = xv.y; Xs[xc + 2][xr] = xv.z; Xs[xc + 3][xr] = xv.w;
    Ws[wc + 0][wr] = wv0.x; Ws[wc + 1][wr] = wv0.y; Ws[wc + 2][wr] = wv0.z; Ws[wc + 3][wr] = wv0.w;
    Ws[wc + 4][wr] = wv1.x; Ws[wc + 5][wr] = wv1.y; Ws[wc + 6][wr] = wv1.z; Ws[wc + 7][wr] = wv1.w;
    __syncthreads();
    if (k0 + 32 < DD) {   // prefetch next k-tile; hides under 256 FMAs below
      xv  = *(const float4*)&X[(m0 + xr) * DD + k0 + 32 + xc];
      wv0 = *(const float4*)&W[(e0 + wr) * DD + k0 + 32 + wc];
      wv1 = *(const float4*)&W[(e0 + wr) * DD + k0 + 32 + wc + 4];
    }
#pragma unroll
    for (int k = 0; k < 32; ++k) {
      const float2 a  = *(const float2*)&Xs[k][r0];
      const float4 bq = *(const float4*)&Ws[k][c0];
      acc[0][0] = fmaf(a.x, bq.x, acc[0][0]); acc[0][1] = fmaf(a.x, bq.y, acc[0][1]);
      acc[0][2] = fmaf(a.x, bq.z, acc[0][2]); acc[0][3] = fmaf(a.x, bq.w, acc[0][3]);
      acc[1][0] = fmaf(a.y, bq.x, acc[1][0]); acc[1][1] = fmaf(a.y, bq.y, acc[1][1]);
      acc[1][2] = fmaf(a.y, bq.z, acc[1][2]); acc[1][3] = fmaf(a.y, bq.w, acc[1][3]);
    }
  }
  if (isK) {
    const int b = m0 >> 9;
    const int kloc = (m0 & 511) + r0;
#pragma unroll
    for (int j = 0; j < 4; ++j) {
      float2 o;
      o.x = fast_exp2(acc[0][j] * TWO_LOG2E);
      o.y = fast_exp2(acc[1][j] * TWO_LOG2E);
      *(float2*)&EaT[b * (DD * LKK) + (e0 + c0 + j) * LKK + kloc] = o;
    }
  } else {
#pragma unroll
    for (int i = 0; i < 2; ++i) {
      float4 o;
      o.x = fast_exp2(acc[i][0] * TWO_LOG2E);
      o.y = fast_exp2(acc[i][1] * TWO_LOG2E);
      o.z = fast_exp2(acc[i][2] * TWO_LOG2E);
      o.w = fast_exp2(acc[i][3] * TWO_LOG2E);
      *(float4*)&Eb[(m0 + r0 + i) * DD + e0 + c0] = o;
    }
  }
}

// 8-way tree: sum over 8 consecutive d of v_d/A_d with ONE rcp.
#define QUAD8(CX, UBL, UBH, ACC) do {                                 \
    const float A_ = fmaf(c0.CX, (UBL).x, 1.f);                       \
    const float B_ = fmaf(c1.CX, (UBL).y, 1.f);                       \
    const float C_ = fmaf(c2.CX, (UBL).z, 1.f);                       \
    const float D_ = fmaf(c3.CX, (UBL).w, 1.f);                       \
    const float E_ = fmaf(c4.CX, (UBH).x, 1.f);                       \
    const float F_ = fmaf(c5.CX, (UBH).y, 1.f);                       \
    const float G_ = fmaf(c6.CX, (UBH).z, 1.f);                       \
    const float H_ = fmaf(c7.CX, (UBH).w, 1.f);                       \
    const float AB_ = A_ * B_, CD_ = C_ * D_;                         \
    const float EF_ = E_ * F_, GH_ = G_ * H_;                         \
    const float t1_ = fmaf(uv0.y, A_, uv0.x * B_);                    \
    const float t2_ = fmaf(uv0.w, C_, uv0.z * D_);                    \
    const float t3_ = fmaf(uv1.y, E_, uv1.x * F_);                    \
    const float t4_ = fmaf(uv1.w, G_, uv1.z * H_);                    \
    const float n1_ = fmaf(t1_, CD_, t2_ * AB_);                      \
    const float n2_ = fmaf(t3_, GH_, t4_ * EF_);                      \
    const float d1_ = AB_ * CD_, d2_ = EF_ * GH_;                     \
    const float nm_ = fmaf(n1_, d2_, n2_ * d1_);                      \
    ACC = fmaf(nm_, fast_rcp(d1_ * d2_), ACC);                        \
  } while (0)

// Scores only, k-split for 4 waves/SIMD: 512 blocks x 512 thr.
// Block = (b, 4 q-rows, 256-k half); thread = (4k x 4q x 32-d slice).
// Raw masked scaled scores -> Sws (attn region of d_out).
__global__ __launch_bounds__(512) void scores_k(const float* __restrict__ EaT,
                                                const float* __restrict__ Eb,
                                                const float* __restrict__ vvec,
                                                const int* __restrict__ mask,
                                                float* __restrict__ Sws) {
  __shared__ float buf[8 * 4 * 256];   // 32 KB: [dh8][q][k-local]
  __shared__ float svs[8];

  const int tid = threadIdx.x;
  const int bid = blockIdx.x;          // 0..511
  const int b  = bid >> 7;
  const int r  = bid & 127;
  const int q0 = (r >> 1) << 2;        // 0..252 step 4
  const int kh = (r & 1) << 8;         // 0 or 256
  const int dh8 = (tid >> 6);          // 0..7 (wave-uniform, 32-d slice)
  const int kt  = tid & 63;
  const int k4l = kt << 2;             // 0..252 (k local within half)
  const int db  = dh8 << 5;            // 0,32,...,224

  // ---- phase 1: scores (4k x 4q) over this wave's 32-d slice ----
  {
    const float* ebp0 = uni(&Eb[(b * LQQ + q0) * DD + db]);
    const float* ebp1 = uni(&Eb[(b * LQQ + q0 + 1) * DD + db]);
    const float* ebp2 = uni(&Eb[(b * LQQ + q0 + 2) * DD + db]);
    const float* ebp3 = uni(&Eb[(b * LQQ + q0 + 3) * DD + db]);
    const float* vp   = uni(&vvec[db]);

    const float* __restrict__ ea = &EaT[b * (DD * LKK) + db * LKK + kh + k4l];
    float4 acc[4] = {};
    float sv = 0.f;

    float4 c0 = *(const float4*)&ea[0 * LKK];
    float4 c1 = *(const float4*)&ea[1 * LKK];
    float4 c2 = *(const float4*)&ea[2 * LKK];
    float4 c3 = *(const float4*)&ea[3 * LKK];
    float4 c4 = *(const float4*)&ea[4 * LKK];
    float4 c5 = *(const float4*)&ea[5 * LKK];
    float4 c6 = *(const float4*)&ea[6 * LKK];
    float4 c7 = *(const float4*)&ea[7 * LKK];
    float4 ubq0l = *(const float4*)&ebp0[0], ubq0h = *(const float4*)&ebp0[4];
    float4 ubq1l = *(const float4*)&ebp1[0], ubq1h = *(const float4*)&ebp1[4];
    float4 ubq2l = *(const float4*)&ebp2[0], ubq2h = *(const float4*)&ebp2[4];
    float4 ubq3l = *(const float4*)&ebp3[0], ubq3h = *(const float4*)&ebp3[4];
    float4 uv0 = *(const float4*)&vp[0], uv1 = *(const float4*)&vp[4];

    for (int d = 0; d < 24; d += 8) {
      const float4 n0 = *(const float4*)&ea[(d +  8) * LKK];
      const float4 n1 = *(const float4*)&ea[(d +  9) * LKK];
      const float4 n2 = *(const float4*)&ea[(d + 10) * LKK];
      const float4 n3 = *(const float4*)&ea[(d + 11) * LKK];
      const float4 n4 = *(const float4*)&ea[(d + 12) * LKK];
      const float4 n5 = *(const float4*)&ea[(d + 13) * LKK];
      const float4 n6 = *(const float4*)&ea[(d + 14) * LKK];
      const float4 n7 = *(const float4*)&ea[(d + 15) * LKK];
      const float4 m0l = *(const float4*)&ebp0[d + 8], m0h = *(const float4*)&ebp0[d + 12];
      const float4 m1l = *(const float4*)&ebp1[d + 8], m1h = *(const float4*)&ebp1[d + 12];
      const float4 m2l = *(const float4*)&ebp2[d + 8], m2h = *(const float4*)&ebp2[d + 12];
      const float4 m3l = *(const float4*)&ebp3[d + 8], m3h = *(const float4*)&ebp3[d + 12];
      const float4 w0 = *(const float4*)&vp[d + 8], w1 = *(const float4*)&vp[d + 12];
      sv += ((uv0.x + uv0.y) + (uv0.z + uv0.w)) + ((uv1.x + uv1.y) + (uv1.z + uv1.w));
      QUAD8(x, ubq0l, ubq0h, acc[0].x); QUAD8(y, ubq0l, ubq0h, acc[0].y);
      QUAD8(z, ubq0l, ubq0h, acc[0].z); QUAD8(w, ubq0l, ubq0h, acc[0].w);
      QUAD8(x, ubq1l, ubq1h, acc[1].x); QUAD8(y, ubq1l, ubq1h, acc[1].y);
      QUAD8(z, ubq1l, ubq1h, acc[1].z); QUAD8(w, ubq1l, ubq1h, acc[1].w);
      QUAD8(x, ubq2l, ubq2h, acc[2].x); QUAD8(y, ubq2l, ubq2h, acc[2].y);
      QUAD8(z, ubq2l, ubq2h, acc[2].z); QUAD8(w, ubq2l, ubq2h, acc[2].w);
      QUAD8(x, ubq3l, ubq3h, acc[3].x); QUAD8(y, ubq3l, ubq3h, acc[3].y);
      QUAD8(z, ubq3l, ubq3h, acc[3].z); QUAD8(w, ubq3l, ubq3h, acc[3].w);
      c0 = n0; c1 = n1; c2 = n2; c3 = n3; c4 = n4; c5 = n5; c6 = n6; c7 = n7;
      ubq0l = m0l; ubq0h = m0h; ubq1l = m1l; ubq1h = m1h;
      ubq2l = m2l; ubq2h = m2h; ubq3l = m3l; ubq3h = m3h;
      uv0 = w0; uv1 = w1;
    }
    sv += ((uv0.x + uv0.y) + (uv0.z + uv0.w)) + ((uv1.x + uv1.y) + (uv1.z + uv1.w));
    QUAD8(x, ubq0l, ubq0h, acc[0].x); QUAD8(y, ubq0l, ubq0h, acc[0].y);
    QUAD8(z, ubq0l, ubq0h, acc[0].z); QUAD8(w, ubq0l, ubq0h, acc[0].w);
    QUAD8(x, ubq1l, ubq1h, acc[1].x); QUAD8(y, ubq1l, ubq1h, acc[1].y);
    QUAD8(z, ubq1l, ubq1h, acc[1].z); QUAD8(w, ubq1l, ubq1h, acc[1].w);
    QUAD8(x, ubq2l, ubq2h, acc[2].x); QUAD8(y, ubq2l, ubq2h, acc[2].y);
    QUAD8(z, ubq2l, ubq2h, acc[2].z); QUAD8(w, ubq2l, ubq2h, acc[2].w);
    QUAD8(x, ubq3l, ubq3h, acc[3].x); QUAD8(y, ubq3l, ubq3h, acc[3].y);
    QUAD8(z, ubq3l, ubq3h, acc[3].z); QUAD8(w, ubq3l, ubq3h, acc[3].w);

#pragma unroll
    for (int q = 0; q < 4; ++q)
      *(float4*)&buf[(dh8 * 4 + q) * 256 + k4l] = acc[q];
    if (kt == 0) svs[dh8] = sv;
  }
  __syncthreads();

  // ---- combine: 512 threads, thread = (q, 2 k) ----
  {
    const int q  = tid >> 7;
    const int kc = (tid & 127) << 1;   // 0..254 local
    const float Sv = ((svs[0] + svs[1]) + (svs[2] + svs[3]))
                   + ((svs[4] + svs[5]) + (svs[6] + svs[7]));
    float2 s = make_float2(0.f, 0.f);
#pragma unroll
    for (int d = 0; d < 8; ++d) {
      const float2 p = *(const float2*)&buf[(d * 4 + q) * 256 + kc];
      s.x += p.x; s.y += p.y;
    }
    const float inv_scale = 0.0625f;  // 1/sqrt(256)
    s.x = (Sv - 2.f * s.x) * inv_scale;
    s.y = (Sv - 2.f * s.y) * inv_scale;
    const int row = (b * LQQ + q0 + q) * LKK + kh + kc;
    const int2 mq = *(const int2*)&mask[row];
    if (mq.x == 0) s.x = -1e10f;
    if (mq.y == 0) s.y = -1e10f;
    *(float2*)&Sws[row] = s;
  }
}

// Softmax + attention out + context. 256 blocks x 512 thr. Block = (b, 4 q).
// attn_io holds raw scores on entry, probabilities on exit.
__global__ __launch_bounds__(512) void smax_ctx(const float* __restrict__ value,
                                                float* attn_io,
                                                float* __restrict__ ctx_out) {
  __shared__ float sc[4][LKK];       // 8 KB
  __shared__ float buf[16 * LKK];    // 32 KB ctx partials (8x4x256 used)

  const int tid = threadIdx.x;
  const int bid = blockIdx.x;        // 0..255
  const int b  = bid >> 6;
  const int q0 = (bid & 63) << 2;

  // stage raw scores (4 rows x 512)
  {
    const int q = tid >> 7, j4 = (tid & 127) << 2;
    *(float4*)&sc[q][j4] = *(const float4*)&attn_io[(b * LQQ + q0 + q) * LKK + j4];
  }
  __syncthreads();

  // softmax: wave w<4 handles q-row w, 8 elems/lane, in-wave reduce
  {
    const int w = tid >> 6, lane = tid & 63;
    if (w < 4) {
      float e_[8];
      float mx = -3.4e38f;
#pragma unroll
      for (int i = 0; i < 8; ++i) { e_[i] = sc[w][(i << 6) + lane]; mx = fmaxf(mx, e_[i]); }
#pragma unroll
      for (int off = 32; off; off >>= 1) mx = fmaxf(mx, __shfl_xor(mx, off));
      float sum = 0.f;
#pragma unroll
      for (int i = 0; i < 8; ++i) { e_[i] = fast_exp2((e_[i] - mx) * LOG2E); sum += e_[i]; }
#pragma unroll
      for (int off = 32; off; off >>= 1) sum += __shfl_xor(sum, off);
      const float inv = fast_rcp(sum);
      const int arow = (b * LQQ + q0 + w) * LKK;
#pragma unroll
      for (int i = 0; i < 8; ++i) {
        const float p = e_[i] * inv;
        attn_io[arow + (i << 6) + lane] = p;
        sc[w][(i << 6) + lane] = p;
      }
    }
  }
  __syncthreads();

  // context: thread = (k-eighth x float4 d, 4 q); LDS reduce via buf
  {
    const int kh = tid >> 6, dv = (tid & 63) << 2;
    const int kb = kh << 6;          // 64-k range
    float4 c[4] = {};
    const float* __restrict__ vb = &value[(b * LKK + kb) * DD + dv];
    for (int s = 0; s < 64; s += 4) {
      const float4 p0v = *(const float4*)&sc[0][kb + s];
      const float4 p1v = *(const float4*)&sc[1][kb + s];
      const float4 p2v = *(const float4*)&sc[2][kb + s];
      const float4 p3v = *(const float4*)&sc[3][kb + s];
#pragma unroll
      for (int u = 0; u < 4; ++u) {
        const float4 vv = *(const float4*)vb; vb += DD;
        const float a0 = COMP(p0v, u), a1 = COMP(p1v, u);
        const float a2 = COMP(p2v, u), a3 = COMP(p3v, u);
        c[0].x = fmaf(a0, vv.x, c[0].x); c[0].y = fmaf(a0, vv.y, c[0].y);
        c[0].z = fmaf(a0, vv.z, c[0].z); c[0].w = fmaf(a0, vv.w, c[0].w);
        c[1].x = fmaf(a1, vv.x, c[1].x); c[1].y = fmaf(a1, vv.y, c[1].y);
        c[1].z = fmaf(a1, vv.z, c[1].z); c[1].w = fmaf(a1, vv.w, c[1].w);
        c[2].x = fmaf(a2, vv.x, c[2].x); c[2].y = fmaf(a2, vv.y, c[2].y);
        c[2].z = fmaf(a2, vv.z, c[2].z); c[2].w = fmaf(a2, vv.w, c[2].w);
        c[3].x = fmaf(a3, vv.x, c[3].x); c[3].y = fmaf(a3, vv.y, c[3].y);
        c[3].z = fmaf(a3, vv.z, c[3].z); c[3].w = fmaf(a3, vv.w, c[3].w);
      }
    }
    __syncthreads();
#pragma unroll
    for (int q = 0; q < 4; ++q)
      *(float4*)&buf[(kh * 4 + q) * DD + dv] = c[q];
  }
  __syncthreads();

  if (tid < 256) {
    const int qq = tid >> 6, d4 = (tid & 63) << 2;
    float4 s4 = make_float4(0.f, 0.f, 0.f, 0.f);
#pragma unroll
    for (int kh2 = 0; kh2 < 8; ++kh2) {
      const float4 rr = *(const float4*)&buf[(kh2 * 4 + qq) * DD + d4];
      s4.x += rr.x; s4.y += rr.y; s4.z += rr.z; s4.w += rr.w;
    }
    *(float4*)&ctx_out[(b * LQQ + q0 + qq) * DD + d4] = s4;
  }
}

extern "C" void kernel_launch(void* const* d_in, const int* in_sizes, int n_in,
                              void* d_out, int out_size, void* d_ws, size_t ws_size,
                              hipStream_t stream) {
  const float* query = (const float*)d_in[0];
  const float* key   = (const float*)d_in[1];
  const float* value = (const float*)d_in[2];
  const float* W1    = (const float*)d_in[3];
  const float* W2    = (const float*)d_in[4];
  const float* v     = (const float*)d_in[5];
  const int*   mask  = (const int*)d_in[6];

  float* out      = (float*)d_out;
  float* ctx_out  = out;                       // [B, LQ, D]
  float* attn_out = out + BB * LQQ * DD;       // [B, LQ, LK] (raw scores, then probs)

  float* EaT = (float*)d_ws;                   // [B][D][LK] = 2 MB
  float* Eb  = EaT + BB * DD * LKK;            // [B*LQ][D]  = 1 MB

  dim3 g1(BB * LKK / 32 + BB * LQQ / 32, DD / 64);   // (96, 4)
  gemm_expk2<<<g1, 256, 0, stream>>>(key, query, W1, W2, EaT, Eb);

  scores_k<<<512, 512, 0, stream>>>(EaT, Eb, v, mask, attn_out);

  smax_ctx<<<256, 512, 0, stream>>>(value, attn_out, ctx_out);
}

// Round 20
// 40.320 us; speedup vs baseline: 1.1511x; 1.1511x over previous
//
#include <hip/hip_runtime.h>
#include <math.h>

#define DD  256
#define LKK 512
#define LQQ 256
#define BB  4

constexpr float TWO_LOG2E = 2.8853900817779268f;  // 2*log2(e)
constexpr float LOG2E     = 1.4426950408889634f;

__device__ __forceinline__ float fast_rcp(float x)  { return __builtin_amdgcn_rcpf(x); }
__device__ __forceinline__ float fast_exp2(float x) { return __builtin_amdgcn_exp2f(x); }

// Force a (group-uniform) pointer into SGPRs so uniform loads can go scalar.
__device__ __forceinline__ const float* uni(const float* p) {
  unsigned long long a = (unsigned long long)p;
  unsigned lo = __builtin_amdgcn_readfirstlane((unsigned)a);
  unsigned hi = __builtin_amdgcn_readfirstlane((unsigned)(a >> 32));
  return (const float*)(((unsigned long long)hi << 32) | lo);
}

#define COMP(v,u) ((u)==0?(v).x:(u)==1?(v).y:(u)==2?(v).z:(v).w)

// EaT[b][e][k] = exp(2 * key[b,k,:] . W1[e,:])  (fp32, d-major / transposed)
// Eb [b*LQ+q][e] = exp(2 * query[b,q,:] . W2[e,:])  (fp32, row-major)
// R14 config verbatim (measured best): BK=32, 32m x 64e tiles, (96,4) grid.
__global__ __launch_bounds__(256) void gemm_expk2(const float* __restrict__ key,
                                                  const float* __restrict__ query,
                                                  const float* __restrict__ W1,
                                                  const float* __restrict__ W2,
                                                  float* __restrict__ EaT,
                                                  float* __restrict__ Eb) {
  __shared__ float Xs[32][36];
  __shared__ float Ws[32][68];
  const int tid = threadIdx.x;
  const bool isK = blockIdx.x < (BB * LKK / 32);
  const float* __restrict__ X = isK ? key : query;
  const float* __restrict__ W = isK ? W1 : W2;
  const int m0 = (isK ? blockIdx.x : blockIdx.x - BB * LKK / 32) * 32;
  const int e0 = blockIdx.y * 64;

  const int r0 = (tid >> 4) << 1;   // 0..30
  const int c0 = (tid & 15) << 2;   // 0..60
  const int xr = tid >> 3, xc = (tid & 7) << 2;   // 32 rows x 32 k via float4
  const int wr = tid >> 2, wc = (tid & 3) << 3;   // 64 rows x 32 k via 2x float4

  float4 xv  = *(const float4*)&X[(m0 + xr) * DD + xc];
  float4 wv0 = *(const float4*)&W[(e0 + wr) * DD + wc];
  float4 wv1 = *(const float4*)&W[(e0 + wr) * DD + wc + 4];

  float acc[2][4] = {};
  for (int k0 = 0; k0 < DD; k0 += 32) {
    __syncthreads();
    Xs[xc + 0][xr] = xv.x; Xs[xc + 1][xr] = xv.y; Xs[xc + 2][xr] = xv.z; Xs[xc + 3][xr] = xv.w;
    Ws[wc + 0][wr] = wv0.x; Ws[wc + 1][wr] = wv0.y; Ws[wc + 2][wr] = wv0.z; Ws[wc + 3][wr] = wv0.w;
    Ws[wc + 4][wr] = wv1.x; Ws[wc + 5][wr] = wv1.y; Ws[wc + 6][wr] = wv1.z; Ws[wc + 7][wr] = wv1.w;
    __syncthreads();
    if (k0 + 32 < DD) {   // prefetch next k-tile; hides under 256 FMAs below
      xv  = *(const float4*)&X[(m0 + xr) * DD + k0 + 32 + xc];
      wv0 = *(const float4*)&W[(e0 + wr) * DD + k0 + 32 + wc];
      wv1 = *(const float4*)&W[(e0 + wr) * DD + k0 + 32 + wc + 4];
    }
#pragma unroll
    for (int k = 0; k < 32; ++k) {
      const float2 a  = *(const float2*)&Xs[k][r0];
      const float4 bq = *(const float4*)&Ws[k][c0];
      acc[0][0] = fmaf(a.x, bq.x, acc[0][0]); acc[0][1] = fmaf(a.x, bq.y, acc[0][1]);
      acc[0][2] = fmaf(a.x, bq.z, acc[0][2]); acc[0][3] = fmaf(a.x, bq.w, acc[0][3]);
      acc[1][0] = fmaf(a.y, bq.x, acc[1][0]); acc[1][1] = fmaf(a.y, bq.y, acc[1][1]);
      acc[1][2] = fmaf(a.y, bq.z, acc[1][2]); acc[1][3] = fmaf(a.y, bq.w, acc[1][3]);
    }
  }
  if (isK) {
    const int b = m0 >> 9;
    const int kloc = (m0 & 511) + r0;
#pragma unroll
    for (int j = 0; j < 4; ++j) {
      float2 o;
      o.x = fast_exp2(acc[0][j] * TWO_LOG2E);
      o.y = fast_exp2(acc[1][j] * TWO_LOG2E);
      *(float2*)&EaT[b * (DD * LKK) + (e0 + c0 + j) * LKK + kloc] = o;
    }
  } else {
#pragma unroll
    for (int i = 0; i < 2; ++i) {
      float4 o;
      o.x = fast_exp2(acc[i][0] * TWO_LOG2E);
      o.y = fast_exp2(acc[i][1] * TWO_LOG2E);
      o.z = fast_exp2(acc[i][2] * TWO_LOG2E);
      o.w = fast_exp2(acc[i][3] * TWO_LOG2E);
      *(float4*)&Eb[(m0 + r0 + i) * DD + e0 + c0] = o;
    }
  }
}

// 8-way tree: sum over 8 consecutive d of v_d/A_d with ONE rcp.
// All factors A = 1+Ea*Eb > 1, so den in (1, ~e^40) — no overflow/underflow.
// c0..c7 = Ea float4 (4 k-lanes) for d..d+7; CX selects the k-lane.
#define QUAD8(CX, UBL, UBH, ACC) do {                                 \
    const float A_ = fmaf(c0.CX, (UBL).x, 1.f);                       \
    const float B_ = fmaf(c1.CX, (UBL).y, 1.f);                       \
    const float C_ = fmaf(c2.CX, (UBL).z, 1.f);                       \
    const float D_ = fmaf(c3.CX, (UBL).w, 1.f);                       \
    const float E_ = fmaf(c4.CX, (UBH).x, 1.f);                       \
    const float F_ = fmaf(c5.CX, (UBH).y, 1.f);                       \
    const float G_ = fmaf(c6.CX, (UBH).z, 1.f);                       \
    const float H_ = fmaf(c7.CX, (UBH).w, 1.f);                       \
    const float AB_ = A_ * B_, CD_ = C_ * D_;                         \
    const float EF_ = E_ * F_, GH_ = G_ * H_;                         \
    const float t1_ = fmaf(uv0.y, A_, uv0.x * B_);                    \
    const float t2_ = fmaf(uv0.w, C_, uv0.z * D_);                    \
    const float t3_ = fmaf(uv1.y, E_, uv1.x * F_);                    \
    const float t4_ = fmaf(uv1.w, G_, uv1.z * H_);                    \
    const float n1_ = fmaf(t1_, CD_, t2_ * AB_);                      \
    const float n2_ = fmaf(t3_, GH_, t4_ * EF_);                      \
    const float d1_ = AB_ * CD_, d2_ = EF_ * GH_;                     \
    const float nm_ = fmaf(n1_, d2_, n2_ * d1_);                      \
    ACC = fmaf(nm_, fast_rcp(d1_ * d2_), ACC);                        \
  } while (0)

// Fused: 8-way-tree scores (4k x 4q x 64-d quarter; float4 Ea loads; uniform
// Eb/v via SGPR pointers) -> softmax -> context. 256 blocks x 512 thr.
__global__ __launch_bounds__(512) void attn_fused(const float* __restrict__ EaT,
                                                  const float* __restrict__ Eb,
                                                  const float* __restrict__ vvec,
                                                  const float* __restrict__ value,
                                                  const int* __restrict__ mask,
                                                  float* __restrict__ ctx_out,
                                                  float* __restrict__ attn_out) {
  __shared__ float sc[4][LKK];       // 8 KB (scores, then probs)
  __shared__ float buf[16 * LKK];    // 32 KB: phase-1 partials, phase-3 scr
  __shared__ float svs[4];           // per-d-group sum of v

  const int tid = threadIdx.x;
  const int bid = blockIdx.x;        // 0..255
  const int b  = bid >> 6;
  const int q0 = (bid & 63) << 2;
  const int dh = tid >> 7;           // 0..3 (wave-uniform, 64-d quarter)
  const int t  = tid & 127;
  const int k4 = t << 2;             // 0..508
  const int db = dh << 6;            // 0,64,128,192

  // ---- phase 1: scores (4k x 4q) over this wave-group's 64-d quarter ----
  {
    // group-uniform SGPR pointers -> scalar loads for the broadcast streams
    const float* ebp0 = uni(&Eb[(b * LQQ + q0) * DD + db]);
    const float* ebp1 = uni(&Eb[(b * LQQ + q0 + 1) * DD + db]);
    const float* ebp2 = uni(&Eb[(b * LQQ + q0 + 2) * DD + db]);
    const float* ebp3 = uni(&Eb[(b * LQQ + q0 + 3) * DD + db]);
    const float* vp   = uni(&vvec[db]);

    const float* __restrict__ ea = &EaT[b * (DD * LKK) + db * LKK + k4];
    float4 acc[4] = {};   // acc[q] = 4 k-lane accumulators (x..w)
    float sv = 0.f;       // sum of v over this group's 64 d

    float4 c0 = *(const float4*)&ea[0 * LKK];
    float4 c1 = *(const float4*)&ea[1 * LKK];
    float4 c2 = *(const float4*)&ea[2 * LKK];
    float4 c3 = *(const float4*)&ea[3 * LKK];
    float4 c4 = *(const float4*)&ea[4 * LKK];
    float4 c5 = *(const float4*)&ea[5 * LKK];
    float4 c6 = *(const float4*)&ea[6 * LKK];
    float4 c7 = *(const float4*)&ea[7 * LKK];
    float4 ubq0l = *(const float4*)&ebp0[0], ubq0h = *(const float4*)&ebp0[4];
    float4 ubq1l = *(const float4*)&ebp1[0], ubq1h = *(const float4*)&ebp1[4];
    float4 ubq2l = *(const float4*)&ebp2[0], ubq2h = *(const float4*)&ebp2[4];
    float4 ubq3l = *(const float4*)&ebp3[0], ubq3h = *(const float4*)&ebp3[4];
    float4 uv0 = *(const float4*)&vp[0], uv1 = *(const float4*)&vp[4];

    for (int d = 0; d < 56; d += 8) {
      // issue next 8-d chunk's loads first; latency hides under 16 trees below
      const float4 n0 = *(const float4*)&ea[(d +  8) * LKK];
      const float4 n1 = *(const float4*)&ea[(d +  9) * LKK];
      const float4 n2 = *(const float4*)&ea[(d + 10) * LKK];
      const float4 n3 = *(const float4*)&ea[(d + 11) * LKK];
      const float4 n4 = *(const float4*)&ea[(d + 12) * LKK];
      const float4 n5 = *(const float4*)&ea[(d + 13) * LKK];
      const float4 n6 = *(const float4*)&ea[(d + 14) * LKK];
      const float4 n7 = *(const float4*)&ea[(d + 15) * LKK];
      const float4 m0l = *(const float4*)&ebp0[d + 8], m0h = *(const float4*)&ebp0[d + 12];
      const float4 m1l = *(const float4*)&ebp1[d + 8], m1h = *(const float4*)&ebp1[d + 12];
      const float4 m2l = *(const float4*)&ebp2[d + 8], m2h = *(const float4*)&ebp2[d + 12];
      const float4 m3l = *(const float4*)&ebp3[d + 8], m3h = *(const float4*)&ebp3[d + 12];
      const float4 w0 = *(const float4*)&vp[d + 8], w1 = *(const float4*)&vp[d + 12];
      sv += ((uv0.x + uv0.y) + (uv0.z + uv0.w)) + ((uv1.x + uv1.y) + (uv1.z + uv1.w));
      QUAD8(x, ubq0l, ubq0h, acc[0].x); QUAD8(y, ubq0l, ubq0h, acc[0].y);
      QUAD8(z, ubq0l, ubq0h, acc[0].z); QUAD8(w, ubq0l, ubq0h, acc[0].w);
      QUAD8(x, ubq1l, ubq1h, acc[1].x); QUAD8(y, ubq1l, ubq1h, acc[1].y);
      QUAD8(z, ubq1l, ubq1h, acc[1].z); QUAD8(w, ubq1l, ubq1h, acc[1].w);
      QUAD8(x, ubq2l, ubq2h, acc[2].x); QUAD8(y, ubq2l, ubq2h, acc[2].y);
      QUAD8(z, ubq2l, ubq2h, acc[2].z); QUAD8(w, ubq2l, ubq2h, acc[2].w);
      QUAD8(x, ubq3l, ubq3h, acc[3].x); QUAD8(y, ubq3l, ubq3h, acc[3].y);
      QUAD8(z, ubq3l, ubq3h, acc[3].z); QUAD8(w, ubq3l, ubq3h, acc[3].w);
      c0 = n0; c1 = n1; c2 = n2; c3 = n3; c4 = n4; c5 = n5; c6 = n6; c7 = n7;
      ubq0l = m0l; ubq0h = m0h; ubq1l = m1l; ubq1h = m1h;
      ubq2l = m2l; ubq2h = m2h; ubq3l = m3l; ubq3h = m3h;
      uv0 = w0; uv1 = w1;
    }
    sv += ((uv0.x + uv0.y) + (uv0.z + uv0.w)) + ((uv1.x + uv1.y) + (uv1.z + uv1.w));
    QUAD8(x, ubq0l, ubq0h, acc[0].x); QUAD8(y, ubq0l, ubq0h, acc[0].y);
    QUAD8(z, ubq0l, ubq0h, acc[0].z); QUAD8(w, ubq0l, ubq0h, acc[0].w);
    QUAD8(x, ubq1l, ubq1h, acc[1].x); QUAD8(y, ubq1l, ubq1h, acc[1].y);
    QUAD8(z, ubq1l, ubq1h, acc[1].z); QUAD8(w, ubq1l, ubq1h, acc[1].w);
    QUAD8(x, ubq2l, ubq2h, acc[2].x); QUAD8(y, ubq2l, ubq2h, acc[2].y);
    QUAD8(z, ubq2l, ubq2h, acc[2].z); QUAD8(w, ubq2l, ubq2h, acc[2].w);
    QUAD8(x, ubq3l, ubq3h, acc[3].x); QUAD8(y, ubq3l, ubq3h, acc[3].y);
    QUAD8(z, ubq3l, ubq3h, acc[3].z); QUAD8(w, ubq3l, ubq3h, acc[3].w);

    // all 4 d-groups publish partials; lane 0 of each group publishes sv
#pragma unroll
    for (int q = 0; q < 4; ++q)
      *(float4*)&buf[(dh * 4 + q) * LKK + k4] = acc[q];
    if (t == 0) svs[dh] = sv;
  }
  __syncthreads();

  // ---- combine: all 512 threads, thread = (q, k-quad) ----
  {
    const int q  = tid >> 7;
    const int kc = (tid & 127) << 2;
    const float Sv = (svs[0] + svs[1]) + (svs[2] + svs[3]);
    const float4 p0 = *(const float4*)&buf[(0 * 4 + q) * LKK + kc];
    const float4 p1 = *(const float4*)&buf[(1 * 4 + q) * LKK + kc];
    const float4 p2 = *(const float4*)&buf[(2 * 4 + q) * LKK + kc];
    const float4 p3 = *(const float4*)&buf[(3 * 4 + q) * LKK + kc];
    const float inv_scale = 0.0625f;  // 1/sqrt(256)
    float4 s;
    s.x = (Sv - 2.f * ((p0.x + p1.x) + (p2.x + p3.x))) * inv_scale;
    s.y = (Sv - 2.f * ((p0.y + p1.y) + (p2.y + p3.y))) * inv_scale;
    s.z = (Sv - 2.f * ((p0.z + p1.z) + (p2.z + p3.z))) * inv_scale;
    s.w = (Sv - 2.f * ((p0.w + p1.w) + (p2.w + p3.w))) * inv_scale;
    const int4 mq = *(const int4*)&mask[(b * LQQ + q0 + q) * LKK + kc];
    if (mq.x == 0) s.x = -1e10f;
    if (mq.y == 0) s.y = -1e10f;
    if (mq.z == 0) s.z = -1e10f;
    if (mq.w == 0) s.w = -1e10f;
    *(float4*)&sc[q][kc] = s;
  }
  __syncthreads();

  // ---- phase 2: softmax (wave w<4 handles q-row w, 8 elems/lane, in-wave) ----
  {
    const int w = tid >> 6, lane = tid & 63;
    if (w < 4) {
      float e_[8];
      float mx = -3.4e38f;
#pragma unroll
      for (int i = 0; i < 8; ++i) { e_[i] = sc[w][(i << 6) + lane]; mx = fmaxf(mx, e_[i]); }
#pragma unroll
      for (int off = 32; off; off >>= 1) mx = fmaxf(mx, __shfl_xor(mx, off));
      float sum = 0.f;
#pragma unroll
      for (int i = 0; i < 8; ++i) { e_[i] = fast_exp2((e_[i] - mx) * LOG2E); sum += e_[i]; }
#pragma unroll
      for (int off = 32; off; off >>= 1) sum += __shfl_xor(sum, off);
      const float inv = fast_rcp(sum);
      const int arow = (b * LQQ + q0 + w) * LKK;
#pragma unroll
      for (int i = 0; i < 8; ++i) {
        const float p = e_[i] * inv;
        attn_out[arow + (i << 6) + lane] = p;
        sc[w][(i << 6) + lane] = p;
      }
    }
  }
  __syncthreads();

  // ---- phase 3: context (thread = k-eighth x float4 d, 4 q; buf as scr) ----
  {
    const int kh = tid >> 6, dv = (tid & 63) << 2;
    const int kb = kh << 6;          // 64-k range
    float4 c[4] = {};
    const float* __restrict__ vb = &value[(b * LKK + kb) * DD + dv];
    for (int s = 0; s < 64; s += 4) {
      const float4 p0v = *(const float4*)&sc[0][kb + s];
      const float4 p1v = *(const float4*)&sc[1][kb + s];
      const float4 p2v = *(const float4*)&sc[2][kb + s];
      const float4 p3v = *(const float4*)&sc[3][kb + s];
#pragma unroll
      for (int u = 0; u < 4; ++u) {
        const float4 vv = *(const float4*)vb; vb += DD;
        const float a0 = COMP(p0v, u), a1 = COMP(p1v, u);
        const float a2 = COMP(p2v, u), a3 = COMP(p3v, u);
        c[0].x = fmaf(a0, vv.x, c[0].x); c[0].y = fmaf(a0, vv.y, c[0].y);
        c[0].z = fmaf(a0, vv.z, c[0].z); c[0].w = fmaf(a0, vv.w, c[0].w);
        c[1].x = fmaf(a1, vv.x, c[1].x); c[1].y = fmaf(a1, vv.y, c[1].y);
        c[1].z = fmaf(a1, vv.z, c[1].z); c[1].w = fmaf(a1, vv.w, c[1].w);
        c[2].x = fmaf(a2, vv.x, c[2].x); c[2].y = fmaf(a2, vv.y, c[2].y);
        c[2].z = fmaf(a2, vv.z, c[2].z); c[2].w = fmaf(a2, vv.w, c[2].w);
        c[3].x = fmaf(a3, vv.x, c[3].x); c[3].y = fmaf(a3, vv.y, c[3].y);
        c[3].z = fmaf(a3, vv.z, c[3].z); c[3].w = fmaf(a3, vv.w, c[3].w);
      }
    }
    __syncthreads();   // all sc/buf reads done before buf reuse as scr
#pragma unroll
    for (int q = 0; q < 4; ++q)
      *(float4*)&buf[(kh * 4 + q) * DD + dv] = c[q];
  }
  __syncthreads();

  if (tid < 256) {
    const int qq = tid >> 6, d4 = (tid & 63) << 2;
    float4 s4 = make_float4(0.f, 0.f, 0.f, 0.f);
#pragma unroll
    for (int kh2 = 0; kh2 < 8; ++kh2) {
      const float4 rr = *(const float4*)&buf[(kh2 * 4 + qq) * DD + d4];
      s4.x += rr.x; s4.y += rr.y; s4.z += rr.z; s4.w += rr.w;
    }
    *(float4*)&ctx_out[(b * LQQ + q0 + qq) * DD + d4] = s4;
  }
}

extern "C" void kernel_launch(void* const* d_in, const int* in_sizes, int n_in,
                              void* d_out, int out_size, void* d_ws, size_t ws_size,
                              hipStream_t stream) {
  const float* query = (const float*)d_in[0];
  const float* key   = (const float*)d_in[1];
  const float* value = (const float*)d_in[2];
  const float* W1    = (const float*)d_in[3];
  const float* W2    = (const float*)d_in[4];
  const float* v     = (const float*)d_in[5];
  const int*   mask  = (const int*)d_in[6];

  float* out      = (float*)d_out;
  float* ctx_out  = out;                       // [B, LQ, D]
  float* attn_out = out + BB * LQQ * DD;       // [B, LQ, LK]

  float* EaT = (float*)d_ws;                   // [B][D][LK] = 2 MB
  float* Eb  = EaT + BB * DD * LKK;            // [B*LQ][D]  = 1 MB

  dim3 g1(BB * LKK / 32 + BB * LQQ / 32, DD / 64);   // (96, 4)
  gemm_expk2<<<g1, 256, 0, stream>>>(key, query, W1, W2, EaT, Eb);

  attn_fused<<<256, 512, 0, stream>>>(EaT, Eb, v, value, mask, ctx_out, attn_out);
}